// Round 5
// baseline (314.002 us; speedup 1.0000x reference)
//
#include <hip/hip_runtime.h>
#include <stdint.h>

#define NTOK 8192
#define NCOL 4096     // DIM == VOCAB
#define RANK 256
#define TPB  32       // tokens per block (r5: halved -> 8 blocks/CU)
#define CPB  512      // cols per block (256 per wave)

typedef __attribute__((ext_vector_type(8))) short bf16x8;
typedef __attribute__((ext_vector_type(4))) float f32x4;

__device__ __forceinline__ unsigned short f2bf(float f) {
    unsigned int u = __float_as_uint(f);
    u += 0x7fffu + ((u >> 16) & 1u);   // RNE
    return (unsigned short)(u >> 16);
}

// ---- pre-pass: B fp32 [256][4096] -> bf16 MFMA-B-fragment order ----
//   frag layout: flat uint4 index = (ct*8 + ks)*64 + lane, 8 bf16 each:
//     element j = B[ks*32 + (lane>>4)*8 + j][ct*16 + (lane&15)]
__global__ __launch_bounds__(256) void prep_B_kernel(
    const float* __restrict__ B, unsigned short* __restrict__ Bfrag)
{
    int gt = blockIdx.x * 256 + threadIdx.x;   // 131072 threads
    int ct = gt >> 9;
    int rem = gt & 511;
    int ks = rem >> 6;
    int ln = rem & 63;
    int col = ct * 16 + (ln & 15);
    int kb  = ks * 32 + ((ln >> 4) << 3);
    unsigned short pk[8];
    #pragma unroll
    for (int j = 0; j < 8; ++j)
        pk[j] = f2bf(B[(size_t)(kb + j) * NCOL + col]);
    uint4 o;
    o.x = (unsigned)pk[0] | ((unsigned)pk[1] << 16);
    o.y = (unsigned)pk[2] | ((unsigned)pk[3] << 16);
    o.z = (unsigned)pk[4] | ((unsigned)pk[5] << 16);
    o.w = (unsigned)pk[6] | ((unsigned)pk[7] << 16);
    reinterpret_cast<uint4*>(Bfrag)[gt] = o;
}

// ---- main: fused gather + A-cast + LoRA GEMM + W add + mask ----
// Block: 32 tokens x 512 cols. 4 waves = 2 token-groups x 2 col-halves.
// 2048 blocks, 16.5 KB LDS, VGPR<=64 -> 8 blocks/CU (32 waves = 100% cap).
__global__ __launch_bounds__(256, 8) void emb_lora_mfma(
    const int* __restrict__ x,
    const int* __restrict__ mask,
    const float* __restrict__ W,
    const float* __restrict__ A,
    const unsigned short* __restrict__ Bfrag,
    float* __restrict__ out)
{
    __shared__ unsigned short a_lds[TPB * RANK];     // 16 KB bf16
    __shared__ int s_idx[TPB];
    __shared__ int s_msk[TPB];

    const int tid  = threadIdx.x;
    const int lane = tid & 63;
    const int wave = tid >> 6;
    const int tg   = wave & 1;        // token group (16 tokens)
    const int ch   = wave >> 1;       // col half (256 cols)
    const int tok0 = blockIdx.x * TPB;
    const int col0 = blockIdx.y * CPB;

    if (tid < TPB) {
        s_idx[tid] = x[tok0 + tid];
        s_msk[tid] = mask[tok0 + tid];
    }
    __syncthreads();

    // stage 32 gathered A rows: fp32 global -> bf16 LDS (cast in-reg).
    // 32 rows x 256 floats = 2048 float4-chunks; 8 per thread.
    #pragma unroll
    for (int it = 0; it < 8; ++it) {
        int c = it * 256 + tid;
        int row = c >> 6;                 // 64 float4-chunks per row
        int off = (c & 63) << 2;          // float offset within row
        float4 v = *reinterpret_cast<const float4*>(
            A + (size_t)s_idx[row] * RANK + off);
        ushort4 o;
        o.x = f2bf(v.x); o.y = f2bf(v.y); o.z = f2bf(v.z); o.w = f2bf(v.w);
        *reinterpret_cast<ushort4*>(a_lds + row * RANK + off) = o;
    }
    __syncthreads();

    // per-wave A fragments: wave owns tokens [tg*16, tg*16+16)
    const int arow = tg * 16 + (lane & 15);
    const unsigned short* ap = a_lds + arow * RANK + ((lane >> 4) << 3);
    bf16x8 afrag[8];
    #pragma unroll
    for (int s = 0; s < 8; ++s)
        afrag[s] = *reinterpret_cast<const bf16x8*>(ap + s * 32);

    // per-thread epilogue state: 4 consecutive token rows, col-half base
    const int rowbase = tg * 16 + ((lane >> 4) << 2);
    const int colb = col0 + ch * 256 + (lane & 15);
    int msk_r[4];
    const float* wptr[4];
    float* optr[4];
    #pragma unroll
    for (int r = 0; r < 4; ++r) {
        int row = rowbase + r;
        msk_r[r] = s_msk[row];
        wptr[r] = W + (size_t)s_idx[row] * NCOL + colb;
        optr[r] = out + (size_t)(tok0 + row) * NCOL + colb;
    }

    // wave's 16 col-tiles start at global col-tile (blockIdx.y*32 + ch*16)
    const uint4* bcol = reinterpret_cast<const uint4*>(Bfrag)
                        + (size_t)(blockIdx.y * 32 + ch * 16) * 512 + lane;

    // W prefetch ring, depth 4, exec-masked loads (keep the explicit `if` —
    // ternary hoisting made the compiler speculate and doubled FETCH_SIZE).
    float wv[4][4];
    #pragma unroll
    for (int p = 0; p < 4; ++p) {
        #pragma unroll
        for (int r = 0; r < 4; ++r) {
            float v = 0.0f;
            if (!msk_r[r]) v = wptr[r][p * 16];
            wv[p][r] = v;
        }
    }

#define TILE_BODY(T, SLOT, PF)                                           \
    {                                                                    \
        const int t_ = (T);                                              \
        uint4 bb[8];                                                     \
        _Pragma("unroll")                                                \
        for (int s = 0; s < 8; ++s)                                      \
            bb[s] = bcol[t_ * 512 + s * 64];                             \
        float wcur[4];                                                   \
        _Pragma("unroll")                                                \
        for (int r = 0; r < 4; ++r) wcur[r] = wv[SLOT][r];               \
        if (PF) {                                                        \
            _Pragma("unroll")                                            \
            for (int r = 0; r < 4; ++r) {                                \
                float v = 0.0f;                                          \
                if (!msk_r[r]) v = wptr[r][(t_ + 4) * 16];               \
                wv[SLOT][r] = v;                                         \
            }                                                            \
        }                                                                \
        f32x4 acc0 = {0.f,0.f,0.f,0.f}, acc1 = {0.f,0.f,0.f,0.f};        \
        _Pragma("unroll")                                                \
        for (int s = 0; s < 4; ++s) {                                    \
            acc0 = __builtin_amdgcn_mfma_f32_16x16x32_bf16(              \
                afrag[s], __builtin_bit_cast(bf16x8, bb[s]), acc0, 0, 0, 0); \
            acc1 = __builtin_amdgcn_mfma_f32_16x16x32_bf16(              \
                afrag[s + 4], __builtin_bit_cast(bf16x8, bb[s + 4]), acc1, 0, 0, 0); \
        }                                                                \
        _Pragma("unroll")                                                \
        for (int r = 0; r < 4; ++r) {                                    \
            float v = msk_r[r] ? 0.0f : (acc0[r] + acc1[r] + wcur[r]);   \
            optr[r][t_ * 16] = v;                                        \
        }                                                                \
    }

    #pragma unroll 1
    for (int t0 = 0; t0 < 12; t0 += 4) {
        TILE_BODY(t0 + 0, 0, 1);
        TILE_BODY(t0 + 1, 1, 1);
        TILE_BODY(t0 + 2, 2, 1);
        TILE_BODY(t0 + 3, 3, 1);
    }
    // peeled tail: no prefetch (avoids OOB reads past the wave's col range)
    TILE_BODY(12, 0, 0);
    TILE_BODY(13, 1, 0);
    TILE_BODY(14, 2, 0);
    TILE_BODY(15, 3, 0);
#undef TILE_BODY
}

extern "C" void kernel_launch(void* const* d_in, const int* in_sizes, int n_in,
                              void* d_out, int out_size, void* d_ws, size_t ws_size,
                              hipStream_t stream) {
    (void)in_sizes; (void)n_in; (void)out_size; (void)ws_size;

    const int*   x    = (const int*)d_in[0];
    const int*   mask = (const int*)d_in[1];
    const float* W    = (const float*)d_in[2];
    const float* A    = (const float*)d_in[3];
    const float* B    = (const float*)d_in[4];
    float*       out  = (float*)d_out;

    unsigned short* Bfrag = (unsigned short*)d_ws;   // 2 MiB

    prep_B_kernel<<<dim3(512), dim3(256), 0, stream>>>(B, Bfrag);

    dim3 grid(NTOK / TPB, NCOL / CPB);   // (256, 8) = 2048 blocks
    emb_lora_mfma<<<grid, dim3(256), 0, stream>>>(x, mask, W, A, Bfrag, out);
}

// Round 6
// 68.158 us; speedup vs baseline: 4.6070x; 4.6070x over previous
//
#include <hip/hip_runtime.h>
#include <stdint.h>

#define NTOK 8192
#define NCOL 4096     // DIM == VOCAB
#define RANK 256
#define TPB  64       // tokens per block (4 waves x 16 tokens)
#define CPB  256      // cols per block (all waves share the B stream)

typedef __attribute__((ext_vector_type(8))) short bf16x8;
typedef __attribute__((ext_vector_type(4))) float f32x4;

__device__ __forceinline__ unsigned short f2bf(float f) {
    unsigned int u = __float_as_uint(f);
    u += 0x7fffu + ((u >> 16) & 1u);   // RNE
    return (unsigned short)(u >> 16);
}

// ---- combined pre-pass ----
// blocks [0, 1024): A fp32 [4096][256] -> bf16 row-major (Abf, 2 MiB, L2-resident)
// blocks [1024, 1536): B fp32 [256][4096] -> bf16 MFMA-B-fragment order
//   frag layout: flat uint4 index = (ct*8 + ks)*64 + lane, 8 bf16 each:
//     element j = B[ks*32 + (lane>>4)*8 + j][ct*16 + (lane&15)]
__global__ __launch_bounds__(256) void prep_kernel(
    const float* __restrict__ A, const float* __restrict__ B,
    unsigned short* __restrict__ Abf, unsigned short* __restrict__ Bfrag)
{
    if (blockIdx.x < 1024) {
        int i = blockIdx.x * 256 + threadIdx.x;
        float4 v = reinterpret_cast<const float4*>(A)[i];
        ushort4 o;
        o.x = f2bf(v.x); o.y = f2bf(v.y); o.z = f2bf(v.z); o.w = f2bf(v.w);
        reinterpret_cast<ushort4*>(Abf)[i] = o;
    } else {
        int gt = (blockIdx.x - 1024) * 256 + threadIdx.x;
        int ct = gt >> 9;
        int rem = gt & 511;
        int ks = rem >> 6;
        int ln = rem & 63;
        int col = ct * 16 + (ln & 15);
        int kb  = ks * 32 + ((ln >> 4) << 3);
        unsigned short pk[8];
        #pragma unroll
        for (int j = 0; j < 8; ++j)
            pk[j] = f2bf(B[(size_t)(kb + j) * NCOL + col]);
        uint4 o;
        o.x = (unsigned)pk[0] | ((unsigned)pk[1] << 16);
        o.y = (unsigned)pk[2] | ((unsigned)pk[3] << 16);
        o.z = (unsigned)pk[4] | ((unsigned)pk[5] << 16);
        o.w = (unsigned)pk[6] | ((unsigned)pk[7] << 16);
        reinterpret_cast<uint4*>(Bfrag)[gt] = o;
    }
}

// ---- main: fused gather + LoRA GEMM + W add + mask ----
// No A-LDS staging: A fragments loaded per-wave from L2-resident Abf.
// LDS ~0.5 KB; VGPR-bound occupancy (~64 VGPR -> 8 waves/SIMD natural).
// Grid 2048 blocks = 8 blocks/CU. NO forced wave minimum (r5 spill lesson).
__global__ __launch_bounds__(256, 4) void emb_lora_mfma(
    const int* __restrict__ x,
    const int* __restrict__ mask,
    const float* __restrict__ W,
    const unsigned short* __restrict__ Abf,
    const unsigned short* __restrict__ Bfrag,
    float* __restrict__ out)
{
    __shared__ int s_idx[TPB];
    __shared__ int s_msk[TPB];

    const int tid  = threadIdx.x;
    const int lane = tid & 63;
    const int wave = tid >> 6;        // token group: wave owns 16 tokens
    const int tok0 = blockIdx.x * TPB;
    const int col0 = blockIdx.y * CPB;

    if (tid < TPB) {
        s_idx[tid] = x[tok0 + tid];
        s_msk[tid] = mask[tok0 + tid];
    }
    __syncthreads();

    // per-wave A fragments, straight from global (Abf is 2 MiB, L2-resident)
    const int arow_idx = s_idx[wave * 16 + (lane & 15)];
    const unsigned short* ap = Abf + (size_t)arow_idx * RANK + ((lane >> 4) << 3);
    bf16x8 afrag[8];
    #pragma unroll
    for (int s = 0; s < 8; ++s)
        afrag[s] = *reinterpret_cast<const bf16x8*>(ap + s * 32);

    // per-thread epilogue state: 4 consecutive token rows
    const int rowbase = wave * 16 + ((lane >> 4) << 2);
    const int colb = col0 + (lane & 15);
    int msk_r[4];
    const float* wptr[4];
    float* optr[4];
    #pragma unroll
    for (int r = 0; r < 4; ++r) {
        int row = rowbase + r;
        msk_r[r] = s_msk[row];
        wptr[r] = W + (size_t)s_idx[row] * NCOL + colb;
        optr[r] = out + (size_t)(tok0 + row) * NCOL + colb;
    }

    // all 4 waves share these 16 col-tiles (B frags L1-resident after wave 0)
    const uint4* bcol = reinterpret_cast<const uint4*>(Bfrag)
                        + (size_t)(blockIdx.y * 16) * 512 + lane;

    // W prefetch ring, depth 4, exec-masked loads (explicit `if`, NOT ternary:
    // ternary hoisting made the compiler speculate -> doubled FETCH_SIZE in r3)
    float wv[4][4];
    #pragma unroll
    for (int p = 0; p < 4; ++p) {
        #pragma unroll
        for (int r = 0; r < 4; ++r) {
            float v = 0.0f;
            if (!msk_r[r]) v = wptr[r][p * 16];
            wv[p][r] = v;
        }
    }

#define TILE_BODY(T, SLOT, PF)                                           \
    {                                                                    \
        const int t_ = (T);                                              \
        uint4 bb[8];                                                     \
        _Pragma("unroll")                                                \
        for (int s = 0; s < 8; ++s)                                      \
            bb[s] = bcol[t_ * 512 + s * 64];                             \
        float wcur[4];                                                   \
        _Pragma("unroll")                                                \
        for (int r = 0; r < 4; ++r) wcur[r] = wv[SLOT][r];               \
        if (PF) {                                                        \
            _Pragma("unroll")                                            \
            for (int r = 0; r < 4; ++r) {                                \
                float v = 0.0f;                                          \
                if (!msk_r[r]) v = wptr[r][(t_ + 4) * 16];               \
                wv[SLOT][r] = v;                                         \
            }                                                            \
        }                                                                \
        f32x4 acc0 = {0.f,0.f,0.f,0.f}, acc1 = {0.f,0.f,0.f,0.f};        \
        _Pragma("unroll")                                                \
        for (int s = 0; s < 4; ++s) {                                    \
            acc0 = __builtin_amdgcn_mfma_f32_16x16x32_bf16(              \
                afrag[s], __builtin_bit_cast(bf16x8, bb[s]), acc0, 0, 0, 0); \
            acc1 = __builtin_amdgcn_mfma_f32_16x16x32_bf16(              \
                afrag[s + 4], __builtin_bit_cast(bf16x8, bb[s + 4]), acc1, 0, 0, 0); \
        }                                                                \
        _Pragma("unroll")                                                \
        for (int r = 0; r < 4; ++r) {                                    \
            float v = msk_r[r] ? 0.0f : (acc0[r] + acc1[r] + wcur[r]);   \
            optr[r][t_ * 16] = v;                                        \
        }                                                                \
    }

    #pragma unroll 1
    for (int t0 = 0; t0 < 12; t0 += 4) {
        TILE_BODY(t0 + 0, 0, 1);
        TILE_BODY(t0 + 1, 1, 1);
        TILE_BODY(t0 + 2, 2, 1);
        TILE_BODY(t0 + 3, 3, 1);
    }
    // peeled tail: no prefetch (avoids OOB reads past the block's col range)
    TILE_BODY(12, 0, 0);
    TILE_BODY(13, 1, 0);
    TILE_BODY(14, 2, 0);
    TILE_BODY(15, 3, 0);
#undef TILE_BODY
}

extern "C" void kernel_launch(void* const* d_in, const int* in_sizes, int n_in,
                              void* d_out, int out_size, void* d_ws, size_t ws_size,
                              hipStream_t stream) {
    (void)in_sizes; (void)n_in; (void)out_size; (void)ws_size;

    const int*   x    = (const int*)d_in[0];
    const int*   mask = (const int*)d_in[1];
    const float* W    = (const float*)d_in[2];
    const float* A    = (const float*)d_in[3];
    const float* B    = (const float*)d_in[4];
    float*       out  = (float*)d_out;

    unsigned short* Abf   = (unsigned short*)d_ws;                       // 2 MiB
    unsigned short* Bfrag = (unsigned short*)((char*)d_ws + (2u << 20)); // 2 MiB

    prep_kernel<<<dim3(1536), dim3(256), 0, stream>>>(A, B, Abf, Bfrag);

    dim3 grid(NTOK / TPB, NCOL / CPB);   // (128, 16) = 2048 blocks
    emb_lora_mfma<<<grid, dim3(256), 0, stream>>>(x, mask, W, Abf, Bfrag, out);
}